// Round 1
// baseline (670.675 us; speedup 1.0000x reference)
//
#include <hip/hip_runtime.h>

// LDPC neural BP decoder, MI355X.
// One block per batch row; full t-row staged in LDS (33.8 KB); vm/vm_prev/wllr
// in registers (17 nodes/thread at 512 threads). t precomputed once per node
// per iteration (10x fewer tanh than per-edge). Gathers are random b32 LDS
// reads -- expected bottleneck this round.

#define NN    8448
#define MAXNB 10
#define TPB   512
#define MAXK  17      // ceil(8448/512); threads 0..255 own 17 nodes, rest 16
#define ITERS 5

__global__ __launch_bounds__(TPB, 4)
void ldpc_decode_kernel(const float* __restrict__ input_llr,
                        const float* __restrict__ w_ch,
                        const float* __restrict__ w_res,   // [2][NN]
                        const int*   __restrict__ cidx,    // [NN][10]
                        float* __restrict__ out)
{
    __shared__ float t_lds[NN];
    const int row = blockIdx.x;
    const int tid = threadIdx.x;
    const float* __restrict__ in_row = input_llr + (size_t)row * NN;

    float vm[MAXK], vmp[MAXK], wl[MAXK];

    // prologue: weighted_llr = input * w_ch; vm0 = weighted_llr; prev = 0
    #pragma unroll
    for (int k = 0; k < MAXK; ++k) {
        int n = tid + k * TPB;
        vmp[k] = 0.0f;
        if (n < NN) {
            float x = in_row[n];          // coalesced
            wl[k] = x * w_ch[n];          // coalesced
            vm[k] = wl[k];
        }
    }

    for (int it = 0; it < ITERS; ++it) {
        // phase 1: t[n] = tanh(clip(0.5*vm, +-9.9))  (exp-based tanh)
        #pragma unroll
        for (int k = 0; k < MAXK; ++k) {
            int n = tid + k * TPB;
            if (n < NN) {
                float y = fminf(fmaxf(0.5f * vm[k], -9.9f), 9.9f);
                float e = __expf(2.0f * y);
                t_lds[n] = 1.0f - __fdividef(2.0f, e + 1.0f);
            }
        }
        __syncthreads();

        // phase 2: gather 10 t's, product, 2*atanh, residual update
        #pragma unroll
        for (int k = 0; k < MAXK; ++k) {
            int n = tid + k * TPB;
            if (n < NN) {
                // 40*n is 8B-aligned -> five int2 loads
                const int2* ip = (const int2*)(cidx + n * MAXNB);
                int2 i0 = ip[0], i1 = ip[1], i2 = ip[2], i3 = ip[3], i4 = ip[4];
                float p0 = t_lds[i0.x] * t_lds[i0.y];
                float p1 = t_lds[i1.x] * t_lds[i1.y];
                float p2 = t_lds[i2.x] * t_lds[i2.y];
                float p3 = t_lds[i3.x] * t_lds[i3.y];
                float p4 = t_lds[i4.x] * t_lds[i4.y];
                float p = ((p0 * p1) * (p2 * p3)) * p4;
                p = fminf(fmaxf(p, -0.999999f), 0.999999f);
                // check = 2*atanh(p) = ln((1+p)/(1-p))
                float check = __logf(__fdividef(1.0f + p, 1.0f - p));
                // residual: w_res[0]*vm + w_res[1]*vm_prev (vmp=0 covers iter 0)
                float nv = wl[k] + check + w_res[n] * vm[k] + w_res[NN + n] * vmp[k];
                vmp[k] = vm[k];
                vm[k]  = nv;
            }
        }
        __syncthreads();
    }

    // epilogue: sigmoid(vm + input)
    #pragma unroll
    for (int k = 0; k < MAXK; ++k) {
        int n = tid + k * TPB;
        if (n < NN) {
            float x = vm[k] + in_row[n];
            out[(size_t)row * NN + n] = __fdividef(1.0f, 1.0f + __expf(-x));
        }
    }
}

extern "C" void kernel_launch(void* const* d_in, const int* in_sizes, int n_in,
                              void* d_out, int out_size, void* d_ws, size_t ws_size,
                              hipStream_t stream) {
    const float* input_llr = (const float*)d_in[0];
    const float* w_ch      = (const float*)d_in[1];
    const float* w_res     = (const float*)d_in[2];
    const int*   cidx      = (const int*)d_in[3];
    // d_in[4] (var_index_tensor) is unused by the reference
    float* out = (float*)d_out;
    int batch = in_sizes[0] / NN;
    hipLaunchKernelGGL(ldpc_decode_kernel, dim3(batch), dim3(TPB), 0, stream,
                       input_llr, w_ch, w_res, cidx, out);
}

// Round 2
// 280.680 us; speedup vs baseline: 2.3895x; 2.3895x over previous
//
#include <hip/hip_runtime.h>

// LDPC neural BP decoder, MI355X. Round 2.
// Round-1 failure mode: vm/vmp/wl[17] per thread spilled to scratch
// (WRITE_SIZE 436 MB vs 34.6 MB output). Fix: TPB=1024 -> 9 nodes/thread,
// state = 27 VGPRs, __launch_bounds__(1024,4) caps VGPR at 128 (no spill).
// One block per batch row; t-row in LDS (33.8 KB); t precomputed per node
// per iteration (10x fewer tanh than per-edge).

#define NN    8448
#define MAXNB 10
#define TPB   1024
#define MAXK  9       // ceil(8448/1024); k=8 active only for tid<256
#define ITERS 5

__global__ __launch_bounds__(TPB, 4)
void ldpc_decode_kernel(const float* __restrict__ input_llr,
                        const float* __restrict__ w_ch,
                        const float* __restrict__ w_res,   // [2][NN]
                        const int*   __restrict__ cidx,    // [NN][10]
                        float* __restrict__ out)
{
    __shared__ float t_lds[NN];
    const int row = blockIdx.x;
    const int tid = threadIdx.x;
    const float* __restrict__ in_row = input_llr + (size_t)row * NN;

    float vm[MAXK], vmp[MAXK], wl[MAXK];

    // prologue: weighted_llr = input * w_ch; vm0 = weighted_llr; prev = 0
    #pragma unroll
    for (int k = 0; k < MAXK; ++k) {
        int n = tid + k * TPB;
        vmp[k] = 0.0f;
        wl[k] = 0.0f;
        vm[k] = 0.0f;
        if (k < MAXK - 1 || n < NN) {
            float x = in_row[n];          // coalesced
            wl[k] = x * w_ch[n];          // coalesced, L2/L3-resident
            vm[k] = wl[k];
        }
    }

    for (int it = 0; it < ITERS; ++it) {
        // phase 1: t[n] = tanh(clip(0.5*vm, +-9.9))
        #pragma unroll
        for (int k = 0; k < MAXK; ++k) {
            int n = tid + k * TPB;
            if (k < MAXK - 1 || n < NN) {
                float y = fminf(fmaxf(0.5f * vm[k], -9.9f), 9.9f);
                float e = __expf(2.0f * y);
                t_lds[n] = 1.0f - __fdividef(2.0f, e + 1.0f);
            }
        }
        __syncthreads();

        // phase 2: gather 10 t's, product, 2*atanh, residual update
        #pragma unroll
        for (int k = 0; k < MAXK; ++k) {
            int n = tid + k * TPB;
            if (k < MAXK - 1 || n < NN) {
                // 40*n is 8B-aligned -> five int2 loads (L2-resident, 338 KB table)
                const int2* ip = (const int2*)(cidx + n * MAXNB);
                int2 i0 = ip[0], i1 = ip[1], i2 = ip[2], i3 = ip[3], i4 = ip[4];
                float p0 = t_lds[i0.x] * t_lds[i0.y];
                float p1 = t_lds[i1.x] * t_lds[i1.y];
                float p2 = t_lds[i2.x] * t_lds[i2.y];
                float p3 = t_lds[i3.x] * t_lds[i3.y];
                float p4 = t_lds[i4.x] * t_lds[i4.y];
                float p = ((p0 * p1) * (p2 * p3)) * p4;
                p = fminf(fmaxf(p, -0.999999f), 0.999999f);
                // check = 2*atanh(p) = ln((1+p)/(1-p))
                float check = __logf(__fdividef(1.0f + p, 1.0f - p));
                float nv = wl[k] + check + w_res[n] * vm[k] + w_res[NN + n] * vmp[k];
                vmp[k] = vm[k];
                vm[k]  = nv;
            }
        }
        __syncthreads();
    }

    // epilogue: sigmoid(vm + input)
    #pragma unroll
    for (int k = 0; k < MAXK; ++k) {
        int n = tid + k * TPB;
        if (k < MAXK - 1 || n < NN) {
            float x = vm[k] + in_row[n];
            out[(size_t)row * NN + n] = __fdividef(1.0f, 1.0f + __expf(-x));
        }
    }
}

extern "C" void kernel_launch(void* const* d_in, const int* in_sizes, int n_in,
                              void* d_out, int out_size, void* d_ws, size_t ws_size,
                              hipStream_t stream) {
    const float* input_llr = (const float*)d_in[0];
    const float* w_ch      = (const float*)d_in[1];
    const float* w_res     = (const float*)d_in[2];
    const int*   cidx      = (const int*)d_in[3];
    // d_in[4] (var_index_tensor) is unused by the reference
    float* out = (float*)d_out;
    int batch = in_sizes[0] / NN;
    hipLaunchKernelGGL(ldpc_decode_kernel, dim3(batch), dim3(TPB), 0, stream,
                       input_llr, w_ch, w_res, cidx, out);
}